// Round 16
// baseline (365.017 us; speedup 1.0000x reference)
//
#include <hip/hip_runtime.h>
#include <cstdint>
#include <cstddef>

typedef unsigned short u16;
typedef __attribute__((ext_vector_type(8))) short short8;
typedef __attribute__((ext_vector_type(4))) float f32x4;
typedef __attribute__((ext_vector_type(16))) float f32x16;

#define MFMA_B16(a,b,c) __builtin_amdgcn_mfma_f32_16x16x32_bf16((a),(b),(c),0,0,0)
#define MFMA32(a,b,c)  __builtin_amdgcn_mfma_f32_32x32x16_bf16((a),(b),(c),0,0,0)

#define S_LEN 2048
#define EMB 2048
#define QKV_N 6144
#define HD 64
#define LAMBDA_INIT_F 0.78360576653162f
#define ONE_MINUS_LI 0.21639423346838f
// exp(s*0.125) == exp2(s * 0.125*log2(e))
#define EXP2_SCALE 0.18033688011112042f

static __device__ __forceinline__ u16 f2bf(float f) {
  unsigned u = __float_as_uint(f);
  unsigned r = ((u >> 16) & 1u) + 0x7fffu;
  return (u16)((u + r) >> 16);
}
static __device__ __forceinline__ float bf2f(u16 h) {
  return __uint_as_float(((unsigned)h) << 16);
}
static __device__ __forceinline__ unsigned cvt_pk_bf16(float lo, float hi) {
  unsigned r;
  asm("v_cvt_pk_bf16_f32 %0, %1, %2" : "=v"(r) : "v"(lo), "v"(hi));
  return r;
}
static __device__ __forceinline__ void gload_lds16(const u16* g, u16* l) {
  __builtin_amdgcn_global_load_lds((const __attribute__((address_space(1))) void*)g,
                                   (__attribute__((address_space(3))) void*)l, 16, 0, 0);
}

// ---------------- f32 -> bf16 convert: all 5 tensors in ONE launch ----------------
__global__ void cvt_all(const float* __restrict__ x,  const float* __restrict__ Wq,
                        const float* __restrict__ Wk, const float* __restrict__ Wv,
                        const float* __restrict__ Wo,
                        u16* __restrict__ xb, u16* __restrict__ Wcat, u16* __restrict__ Wob) {
  const int NE = EMB * EMB;
  const int NE4 = NE / 4;
  int i = blockIdx.x * 256 + threadIdx.x;
  const float* s; u16* d; int j;
  if (i < 2 * NE4)      { s = x;  d = xb;            j = i;           }
  else if (i < 3 * NE4) { s = Wq; d = Wcat;          j = i - 2 * NE4; }
  else if (i < 4 * NE4) { s = Wk; d = Wcat + NE;     j = i - 3 * NE4; }
  else if (i < 5 * NE4) { s = Wv; d = Wcat + 2 * NE; j = i - 4 * NE4; }
  else                  { s = Wo; d = Wob;           j = i - 5 * NE4; }
  f32x4 v = *(const f32x4*)&s[j * 4];
  unsigned lo = cvt_pk_bf16(v[0], v[1]);
  unsigned hi = cvt_pk_bf16(v[2], v[3]);
  *(unsigned long long*)&d[j * 4] = (unsigned long long)lo | ((unsigned long long)hi << 32);
}

// ---------------- RoPE cos/sin table: tab[t*32+p] = {cos(t*w_p), sin(t*w_p)} ----------------
__global__ void rope_table(float2* __restrict__ tab) {
  int idx = blockIdx.x * 256 + threadIdx.x;   // 65536 = 2048 t x 32 p
  int t = idx >> 5;
  int p = idx & 31;
  float w = expf((float)p * (-9.210340371976184f / 31.0f));
  float sn, cs;
  sincosf((float)t * w, &sn, &cs);
  tab[idx] = make_float2(cs, sn);
}

// ---------------- GEMM v2: C[M,N] = A[M,K] * B[N,K]^T  (bf16 in, f32 acc) ----------------
// BM=128, BN=256, BK=64; 512 threads (8 waves, 2 row x 4 col groups, 64x64 each).
// LDS double-buffered; ONE barrier per K-tile; stages issued BEFORE compute.
// MODE 1: bf16 out + fused interleaved RoPE on q/k column regions (blockIdx.y < 16).
// MODE 0: f32 out.
#define SWG(row, colByte) (((row) << 7) + ((colByte) ^ (((row) & 7) << 4)))

template <int MODE>
__global__ __launch_bounds__(512, 2) void gemm2(const u16* __restrict__ A,
                                                const u16* __restrict__ B,
                                                void* __restrict__ Cout,
                                                const float2* __restrict__ rtab,
                                                int M, int N, int K) {
  __shared__ u16 As[2][128 * 64];       // 32 KB
  __shared__ u16 Bs[2][2][128 * 64];    // 64 KB
  const int tid = threadIdx.x;
  const int lane = tid & 63, wv = tid >> 6;
  const int wr = wv >> 2, wc = wv & 3;
  const int lr = lane & 15, hk = lane >> 4;
  const int bm = blockIdx.x * 128, bn = blockIdx.y * 256;

  const int srow = tid >> 3;            // 0..63
  const int ssb  = tid & 7;             // 16B slot
  const int scb  = (ssb ^ (srow & 7)) * 8;   // pre-swizzled source col (elems)
  const u16* gA = A + (size_t)(bm + srow) * K + scb;
  const u16* gB = B + (size_t)(bn + srow) * K + scb;
  const int ldst = srow * 64 + ssb * 8;      // linear LDS elem offset

  f32x4 acc[4][4] = {};

#define STAGE2(buf, k0_) do {                                              \
    gload_lds16(gA + (k0_),                   &As[buf][ldst]);             \
    gload_lds16(gA + (size_t)64  * K + (k0_), &As[buf][ldst + 64 * 64]);   \
    gload_lds16(gB + (k0_),                   &Bs[buf][0][ldst]);          \
    gload_lds16(gB + (size_t)64  * K + (k0_), &Bs[buf][0][ldst + 64 * 64]);\
    gload_lds16(gB + (size_t)128 * K + (k0_), &Bs[buf][1][ldst]);          \
    gload_lds16(gB + (size_t)192 * K + (k0_), &Bs[buf][1][ldst + 64 * 64]);\
  } while (0)

  STAGE2(0, 0);
  __syncthreads();
  int cur = 0;
  const int br = (wc & 1) * 64;

  for (int k0 = 0; k0 < K; k0 += 64) {
    if (k0 + 64 < K) STAGE2(cur ^ 1, k0 + 64);   // in flight during compute
    const char* aH = (const char*)&As[cur][0];
    const char* bH = (const char*)&Bs[cur][wc >> 1][0];
#pragma unroll
    for (int kk = 0; kk < 2; kk++) {
      short8 af[4], bfv[4];
#pragma unroll
      for (int i = 0; i < 4; i++)
        af[i] = *(const short8*)(aH + SWG(wr * 64 + i * 16 + lr, kk * 64 + hk * 16));
#pragma unroll
      for (int j = 0; j < 4; j++)
        bfv[j] = *(const short8*)(bH + SWG(br + j * 16 + lr, kk * 64 + hk * 16));
#pragma unroll
      for (int i = 0; i < 4; i++)
#pragma unroll
        for (int j = 0; j < 4; j++)
          acc[i][j] = MFMA_B16(af[i], bfv[j], acc[i][j]);
    }
    __syncthreads();
    cur ^= 1;
  }
#undef STAGE2

  if (MODE == 1) {
    u16* C = (u16*)Cout;
    const bool dorope = (blockIdx.y < 16);   // q/k column regions; block-uniform
    const int odd = lane & 1;
#pragma unroll
    for (int i = 0; i < 4; i++)
#pragma unroll
      for (int j = 0; j < 4; j++)
#pragma unroll
        for (int r = 0; r < 4; r++) {
          int row = bm + wr * 64 + i * 16 + hk * 4 + r;
          int col = bn + wc * 64 + j * 16 + lr;
          float v = acc[i][j][r];
          if (dorope) {
            // RoPE pair (2p,2p+1) = adjacent lanes (lr, lr^1) at same (i,j,r).
            float o = __shfl_xor(v, 1);
            int t = row & (S_LEN - 1);
            int p = (col & 63) >> 1;
            float2 cs = rtab[t * 32 + p];
            float os = o * cs.y;
            v = fmaf(v, cs.x, odd ? os : -os);   // even: v*c - o*s ; odd: v*c + o*s
          }
          C[(size_t)row * N + col] = f2bf(v);
        }
  } else {
    float* C = (float*)Cout;
#pragma unroll
    for (int i = 0; i < 4; i++)
#pragma unroll
      for (int j = 0; j < 4; j++)
#pragma unroll
        for (int r = 0; r < 4; r++) {
          int row = bm + wr * 64 + i * 16 + hk * 4 + r;
          int col = bn + wc * 64 + j * 16 + lr;
          C[(size_t)row * N + col] = acc[i][j][r];
        }
  }
}

// ---------------- fused dual-stream attention + lambda-combine + RMSNorm ----------------
// (r9 structure verbatim — session-best 175.9 us)
#define SW(row, colByte) ((((row)) << 7) + ((colByte) ^ (((row) & 7) << 4)))

__global__ __launch_bounds__(256, 2) void attn_kernel(
    const u16* __restrict__ qkv, u16* __restrict__ attnb,
    const float* __restrict__ lq1, const float* __restrict__ lk1,
    const float* __restrict__ lq2, const float* __restrict__ lk2,
    const float* __restrict__ gamma) {
  __shared__ u16 K1s[64 * 64];
  __shared__ u16 K2s[64 * 64];
  __shared__ u16 VTs[128 * 64];
  __shared__ u16 Ps[2 * 2 * 32 * 64];   // [q-group][stream][32 q][64 kv]
  __shared__ float Lr[2][2][2][32];     // [q-group][stream][dh][q]
  __shared__ float Sr[2][2][32];        // [q-group][dh][q]

  const int g = blockIdx.x;       // 1024 blocks
  const int xcd = g & 7;
  const int gi = g >> 3;          // 0..127
  const int bh = xcd * 4 + (gi >> 5);
  const int qt = gi & 31;         // 32 q-tiles of 64 rows
  const int b = bh >> 4, h = bh & 15;

  const int tid = threadIdx.x, lane = tid & 63, wv = tid >> 6;
  const int qg = wv >> 1;         // q-group (0,1)
  const int dh = wv & 1;          // d-half (0,1); also this wave's KT in QK^T
  const int l31 = lane & 31;
  const int hi16 = (lane >> 5) * 16;
  const int hi8 = (lane >> 5) * 8;
  const int hi4 = (lane >> 5) * 4;

  float d1 = lq1[lane] * lk1[lane];
  float d2 = lq2[lane] * lk2[lane];
#pragma unroll
  for (int off = 32; off; off >>= 1) { d1 += __shfl_xor(d1, off); d2 += __shfl_xor(d2, off); }
  const float lam = __expf(d1) - __expf(d2) + LAMBDA_INIT_F;

  const int qbase = qt * 64 + qg * 32;
  const u16* qp1 = qkv + (size_t)(b * S_LEN + qbase + l31) * QKV_N + (2 * h) * 64;
  const u16* qp2 = qp1 + 64;
  short8 q1f0 = *(const short8*)(qp1 + hi8);
  short8 q1f1 = *(const short8*)(qp1 + 16 + hi8);
  short8 q1f2 = *(const short8*)(qp1 + 32 + hi8);
  short8 q1f3 = *(const short8*)(qp1 + 48 + hi8);
  short8 q2f0 = *(const short8*)(qp2 + hi8);
  short8 q2f1 = *(const short8*)(qp2 + 16 + hi8);
  short8 q2f2 = *(const short8*)(qp2 + 32 + hi8);
  short8 q2f3 = *(const short8*)(qp2 + 48 + hi8);

  f32x16 o1t0 = {}, o1t1 = {}, o2t0 = {}, o2t1 = {};
  float l1p = 0.f, l2p = 0.f;

  const int gl_row = wv * 8 + (lane >> 3);
  const int gl_cb  = ((lane & 7) ^ (lane >> 3)) * 8;
  u16* k1d = &K1s[(wv * 8) * 64 + lane * 8];
  u16* k2d = &K2s[(wv * 8) * 64 + lane * 8];

  const int vkv = (tid & 31) * 2;
  const int vd0 = (tid >> 5) * 8;

  const u16* kb1 = qkv + (size_t)b * S_LEN * QKV_N + EMB + (2 * h) * 64;
  const u16* kb2 = kb1 + 64;
  const u16* vbp = qkv + (size_t)b * S_LEN * QKV_N + 2 * EMB + h * 128;

  char* K1c = (char*)K1s;
  char* K2c = (char*)K2s;
  char* VTc = (char*)VTs;
  char* P1c = (char*)&Ps[(qg * 2 + 0) * 32 * 64];
  char* P2c = (char*)&Ps[(qg * 2 + 1) * 32 * 64];

  for (int kv0 = 0; kv0 < S_LEN; kv0 += 64) {
    __syncthreads();
    {
      const u16* g1 = kb1 + (size_t)(kv0 + gl_row) * QKV_N + gl_cb;
      const u16* g2 = kb2 + (size_t)(kv0 + gl_row) * QKV_N + gl_cb;
      gload_lds16(g1, k1d);
      gload_lds16(g1 + (size_t)32 * QKV_N, k1d + 32 * 64);
      gload_lds16(g2, k2d);
      gload_lds16(g2 + (size_t)32 * QKV_N, k2d + 32 * 64);
    }
    {
      const u16* vs = vbp + (size_t)(kv0 + vkv) * QKV_N + vd0;
      short8 a0 = *(const short8*)vs;
      short8 a1 = *(const short8*)(vs + QKV_N);
      short8 b0 = *(const short8*)(vs + 64);
      short8 b1 = *(const short8*)(vs + QKV_N + 64);
#pragma unroll
      for (int j = 0; j < 8; j++) {
        unsigned pk0 = (unsigned)(u16)a0[j] | (((unsigned)(u16)a1[j]) << 16);
        *(unsigned*)(VTc + SW(vd0 + j, vkv * 2)) = pk0;
        unsigned pk1 = (unsigned)(u16)b0[j] | (((unsigned)(u16)b1[j]) << 16);
        *(unsigned*)(VTc + SW(vd0 + 64 + j, vkv * 2)) = pk1;
      }
    }
    __syncthreads();

#define QKT(Kc, Q0, Q1, Q2, Q3, Pc, LSUM)                                        \
    do {                                                                         \
      f32x16 s = {};                                                             \
      int row = dh * 32 + l31;                                                   \
      s = MFMA32(*(const short8*)((Kc) + SW(row, 0  + hi16)), Q0, s);            \
      s = MFMA32(*(const short8*)((Kc) + SW(row, 32 + hi16)), Q1, s);            \
      s = MFMA32(*(const short8*)((Kc) + SW(row, 64 + hi16)), Q2, s);            \
      s = MFMA32(*(const short8*)((Kc) + SW(row, 96 + hi16)), Q3, s);            \
      _Pragma("unroll") for (int r = 0; r < 16; r += 4) {                        \
        float e0 = __builtin_amdgcn_exp2f(s[r]     * EXP2_SCALE);                \
        float e1 = __builtin_amdgcn_exp2f(s[r + 1] * EXP2_SCALE);                \
        float e2 = __builtin_amdgcn_exp2f(s[r + 2] * EXP2_SCALE);                \
        float e3 = __builtin_amdgcn_exp2f(s[r + 3] * EXP2_SCALE);                \
        LSUM += (e0 + e1) + (e2 + e3);                                           \
        unsigned lo_ = cvt_pk_bf16(e0, e1);                                      \
        unsigned hi_ = cvt_pk_bf16(e2, e3);                                      \
        *(unsigned long long*)((Pc) + SW(l31, dh * 64 + (r >> 2) * 16 + hi8)) =  \
            (unsigned long long)lo_ | ((unsigned long long)hi_ << 32);           \
      }                                                                          \
    } while (0)
    QKT(K1c, q1f0, q1f1, q1f2, q1f3, P1c, l1p);
    QKT(K2c, q2f0, q2f1, q2f2, q2f3, P2c, l2p);
#undef QKT
    __syncthreads();

    short8 p1f0 = *(const short8*)(P1c + SW(l31, 0  + hi16));
    short8 p1f1 = *(const short8*)(P1c + SW(l31, 32 + hi16));
    short8 p1f2 = *(const short8*)(P1c + SW(l31, 64 + hi16));
    short8 p1f3 = *(const short8*)(P1c + SW(l31, 96 + hi16));
    short8 p2f0 = *(const short8*)(P2c + SW(l31, 0  + hi16));
    short8 p2f1 = *(const short8*)(P2c + SW(l31, 32 + hi16));
    short8 p2f2 = *(const short8*)(P2c + SW(l31, 64 + hi16));
    short8 p2f3 = *(const short8*)(P2c + SW(l31, 96 + hi16));

#define PVD(DT, O1, O2)                                                          \
    do {                                                                         \
      int rw = (DT) * 32 + l31;                                                  \
      short8 va0 = *(const short8*)(VTc + SW(rw, 0  + hi16));                    \
      short8 va1 = *(const short8*)(VTc + SW(rw, 32 + hi16));                    \
      short8 va2 = *(const short8*)(VTc + SW(rw, 64 + hi16));                    \
      short8 va3 = *(const short8*)(VTc + SW(rw, 96 + hi16));                    \
      O1 = MFMA32(va0, p1f0, O1); O1 = MFMA32(va1, p1f1, O1);                    \
      O1 = MFMA32(va2, p1f2, O1); O1 = MFMA32(va3, p1f3, O1);                    \
      O2 = MFMA32(va0, p2f0, O2); O2 = MFMA32(va1, p2f1, O2);                    \
      O2 = MFMA32(va2, p2f2, O2); O2 = MFMA32(va3, p2f3, O2);                    \
    } while (0)
    PVD(dh * 2 + 0, o1t0, o2t0);
    PVD(dh * 2 + 1, o1t1, o2t1);
#undef PVD
  }

  // ---- epilogue ----
  float l1 = l1p + __shfl_xor(l1p, 32);
  float l2 = l2p + __shfl_xor(l2p, 32);
  if (lane < 32) { Lr[qg][0][dh][l31] = l1; Lr[qg][1][dh][l31] = l2; }
  __syncthreads();
  const float inv1 = 1.f / (Lr[qg][0][0][l31] + Lr[qg][0][1][l31]);
  const float inv2 = 1.f / (Lr[qg][1][0][l31] + Lr[qg][1][1][l31]);

  float ss = 0.f;
#define COMB(O1, O2)                                                   \
  _Pragma("unroll") for (int i = 0; i < 16; i++) {                     \
    float a = O1[i] * inv1 - lam * (O2[i] * inv2);                     \
    O1[i] = a;                                                         \
    ss += a * a;                                                       \
  }
  COMB(o1t0, o2t0) COMB(o1t1, o2t1)
#undef COMB
  ss += __shfl_xor(ss, 32);
  if (lane < 32) Sr[qg][dh][l31] = ss;
  __syncthreads();
  const float SS = Sr[qg][0][l31] + Sr[qg][1][l31];
  const float sc2 = rsqrtf(SS * (1.f / 128.f) + 1e-5f) * ONE_MINUS_LI;

  u16* orow = attnb + (size_t)(b * S_LEN + qbase + l31) * EMB + h * 128;
#define WRT(O1, DT)                                                             \
  _Pragma("unroll") for (int gg = 0; gg < 4; gg++) {                            \
    int d = dh * 64 + (DT) * 32 + gg * 8 + hi4;                                 \
    f32x4 gv = *(const f32x4*)&gamma[d];                                        \
    unsigned wlo = cvt_pk_bf16(O1[4 * gg] * gv[0] * sc2, O1[4 * gg + 1] * gv[1] * sc2); \
    unsigned whi = cvt_pk_bf16(O1[4 * gg + 2] * gv[2] * sc2, O1[4 * gg + 3] * gv[3] * sc2); \
    *(unsigned long long*)&orow[d] = (unsigned long long)wlo | ((unsigned long long)whi << 32); \
  }
  WRT(o1t0, 0) WRT(o1t1, 1)
#undef WRT
}

// ---------------- launcher ----------------
extern "C" void kernel_launch(void* const* d_in, const int* in_sizes, int n_in,
                              void* d_out, int out_size, void* d_ws, size_t ws_size,
                              hipStream_t stream) {
  (void)in_sizes; (void)n_in; (void)out_size; (void)ws_size;
  const float* x   = (const float*)d_in[0];
  const float* Wq  = (const float*)d_in[1];
  const float* Wk  = (const float*)d_in[2];
  const float* Wv  = (const float*)d_in[3];
  const float* Wo  = (const float*)d_in[4];
  const float* lq1 = (const float*)d_in[5];
  const float* lk1 = (const float*)d_in[6];
  const float* lq2 = (const float*)d_in[7];
  const float* lk2 = (const float*)d_in[8];
  const float* gam = (const float*)d_in[9];

  char* ws = (char*)d_ws;
  u16* xb    = (u16*)(ws);                          // 4096x2048 bf16
  u16* Wcat  = (u16*)(ws + 16777216);               // 6144x2048 bf16
  u16* Wob   = (u16*)(ws + 41943040);               // 2048x2048 bf16
  u16* qkv   = (u16*)(ws + 50331648);               // 4096x6144 bf16
  float2* rt = (float2*)(ws + 100663296);           // 2048x32 float2 (512 KB)
  u16* attnb = xb;                                  // alias: x dead after QKV GEMM

  const int NE = EMB * EMB;
  cvt_all<<<(6 * (NE / 4)) / 256, 256, 0, stream>>>(x, Wq, Wk, Wv, Wo, xb, Wcat, Wob);
  rope_table<<<(S_LEN * 32) / 256, 256, 0, stream>>>(rt);

  dim3 g1(4096 / 128, QKV_N / 256);
  gemm2<1><<<g1, 512, 0, stream>>>(xb, Wcat, qkv, rt, 4096, QKV_N, EMB);

  attn_kernel<<<1024, 256, 0, stream>>>(qkv, attnb, lq1, lk1, lq2, lk2, gam);

  dim3 g2(4096 / 128, EMB / 256);
  gemm2<0><<<g2, 512, 0, stream>>>(attnb, Wob, d_out, nullptr, 4096, EMB, EMB);
}

// Round 17
// 349.342 us; speedup vs baseline: 1.0449x; 1.0449x over previous
//
#include <hip/hip_runtime.h>
#include <cstdint>
#include <cstddef>

typedef unsigned short u16;
typedef __attribute__((ext_vector_type(8))) short short8;
typedef __attribute__((ext_vector_type(4))) float f32x4;
typedef __attribute__((ext_vector_type(16))) float f32x16;

#define MFMA_B16(a,b,c) __builtin_amdgcn_mfma_f32_16x16x32_bf16((a),(b),(c),0,0,0)
#define MFMA32(a,b,c)  __builtin_amdgcn_mfma_f32_32x32x16_bf16((a),(b),(c),0,0,0)

#define S_LEN 2048
#define EMB 2048
#define QKV_N 6144
#define HD 64
#define LAMBDA_INIT_F 0.78360576653162f
#define ONE_MINUS_LI 0.21639423346838f
// exp(s*0.125) == exp2(s * 0.125*log2(e))
#define EXP2_SCALE 0.18033688011112042f

static __device__ __forceinline__ u16 f2bf(float f) {
  unsigned u = __float_as_uint(f);
  unsigned r = ((u >> 16) & 1u) + 0x7fffu;
  return (u16)((u + r) >> 16);
}
static __device__ __forceinline__ float bf2f(u16 h) {
  return __uint_as_float(((unsigned)h) << 16);
}
static __device__ __forceinline__ unsigned cvt_pk_bf16(float lo, float hi) {
  unsigned r;
  asm("v_cvt_pk_bf16_f32 %0, %1, %2" : "=v"(r) : "v"(lo), "v"(hi));
  return r;
}
static __device__ __forceinline__ void gload_lds16(const u16* g, u16* l) {
  __builtin_amdgcn_global_load_lds((const __attribute__((address_space(1))) void*)g,
                                   (__attribute__((address_space(3))) void*)l, 16, 0, 0);
}

// ---------------- f32 -> bf16 convert: all 5 tensors in ONE launch ----------------
__global__ void cvt_all(const float* __restrict__ x,  const float* __restrict__ Wq,
                        const float* __restrict__ Wk, const float* __restrict__ Wv,
                        const float* __restrict__ Wo,
                        u16* __restrict__ xb, u16* __restrict__ Wcat, u16* __restrict__ Wob) {
  const int NE = EMB * EMB;
  const int NE4 = NE / 4;
  int i = blockIdx.x * 256 + threadIdx.x;
  const float* s; u16* d; int j;
  if (i < 2 * NE4)      { s = x;  d = xb;            j = i;           }
  else if (i < 3 * NE4) { s = Wq; d = Wcat;          j = i - 2 * NE4; }
  else if (i < 4 * NE4) { s = Wk; d = Wcat + NE;     j = i - 3 * NE4; }
  else if (i < 5 * NE4) { s = Wv; d = Wcat + 2 * NE; j = i - 4 * NE4; }
  else                  { s = Wo; d = Wob;           j = i - 5 * NE4; }
  f32x4 v = *(const f32x4*)&s[j * 4];
  unsigned lo = cvt_pk_bf16(v[0], v[1]);
  unsigned hi = cvt_pk_bf16(v[2], v[3]);
  *(unsigned long long*)&d[j * 4] = (unsigned long long)lo | ((unsigned long long)hi << 32);
}

// ---------------- GEMM: C[M,N] = A[M,K] * B[N,K]^T  (bf16 in, f32 acc) ----------------
// m97 structure: 128x128 tile, BK=32, 4 waves, global_load_lds w16. (r0-r14 verified)
template <int BF16OUT>
__global__ __launch_bounds__(256, 2) void gemm_bt(const u16* __restrict__ A,
                                                  const u16* __restrict__ B,
                                                  void* __restrict__ Cout,
                                                  int M, int N, int K) {
  __shared__ u16 As[128 * 32];
  __shared__ u16 Bs[128 * 32];
  const int tid = threadIdx.x;
  const int lane = tid & 63, wv = tid >> 6;
  const int bm = blockIdx.x * 128, bn = blockIdx.y * 128;
  const int wr = (wv >> 1) * 64, wc = (wv & 1) * 64;
  const int lr = lane & 15, hk = lane >> 4;

  const int r0 = tid >> 2;
  const int c0 = (tid & 3) * 8;
  const u16* ga = A + (size_t)(bm + r0) * K + c0;
  const u16* gb = B + (size_t)(bn + r0) * K + c0;
  const size_t rstep = (size_t)64 * K;

  f32x4 acc[4][4] = {};

  for (int k0 = 0; k0 < K; k0 += 32) {
    __syncthreads();
    gload_lds16(ga + k0,         &As[(tid) * 8]);
    gload_lds16(ga + rstep + k0, &As[(tid + 256) * 8]);
    gload_lds16(gb + k0,         &Bs[(tid) * 8]);
    gload_lds16(gb + rstep + k0, &Bs[(tid + 256) * 8]);
    __syncthreads();
    short8 af[4], bfv[4];
#pragma unroll
    for (int i = 0; i < 4; i++) af[i] = *(const short8*)&As[(wr + i * 16 + lr) * 32 + hk * 8];
#pragma unroll
    for (int j = 0; j < 4; j++) bfv[j] = *(const short8*)&Bs[(wc + j * 16 + lr) * 32 + hk * 8];
#pragma unroll
    for (int i = 0; i < 4; i++)
#pragma unroll
      for (int j = 0; j < 4; j++)
        acc[i][j] = MFMA_B16(af[i], bfv[j], acc[i][j]);
  }

  if (BF16OUT) {
    u16* C = (u16*)Cout;
#pragma unroll
    for (int i = 0; i < 4; i++)
#pragma unroll
      for (int j = 0; j < 4; j++)
#pragma unroll
        for (int r = 0; r < 4; r++) {
          int row = bm + wr + i * 16 + hk * 4 + r;
          int col = bn + wc + j * 16 + lr;
          C[(size_t)row * N + col] = f2bf(acc[i][j][r]);
        }
  } else {
    float* C = (float*)Cout;
#pragma unroll
    for (int i = 0; i < 4; i++)
#pragma unroll
      for (int j = 0; j < 4; j++)
#pragma unroll
        for (int r = 0; r < 4; r++) {
          int row = bm + wr + i * 16 + hk * 4 + r;
          int col = bn + wc + j * 16 + lr;
          C[(size_t)row * N + col] = acc[i][j][r];
        }
  }
}

// ---------------- RoPE (interleaved, in place on q,k halves of qkv) ----------------
__global__ void rope_kernel(u16* __restrict__ qkv) {
  int idx = blockIdx.x * 256 + threadIdx.x;
  int p = idx & 31;
  int u = (idx >> 5) & 63;
  int m = idx >> 11;
  int t = m & (S_LEN - 1);
  int col = (u < 32) ? (u * 64 + 2 * p) : (EMB + (u - 32) * 64 + 2 * p);
  u16* ptr = qkv + (size_t)m * QKV_N + col;
  unsigned v = *(unsigned*)ptr;
  float xe = bf2f((u16)(v & 0xffff));
  float xo = bf2f((u16)(v >> 16));
  float w = expf((float)p * (-9.210340371976184f / 31.0f));
  float ang = (float)t * w;
  float sn, cs;
  sincosf(ang, &sn, &cs);
  float oe = xe * cs - xo * sn;
  float oo = xe * sn + xo * cs;
  *(unsigned*)ptr = (unsigned)f2bf(oe) | (((unsigned)f2bf(oo)) << 16);
}

// ---------------- fused dual-stream attention + lambda-combine + RMSNorm ----------------
// (r9 structure verbatim — session-best 175 us)
#define SW(row, colByte) ((((row)) << 7) + ((colByte) ^ (((row) & 7) << 4)))

__global__ __launch_bounds__(256, 2) void attn_kernel(
    const u16* __restrict__ qkv, u16* __restrict__ attnb,
    const float* __restrict__ lq1, const float* __restrict__ lk1,
    const float* __restrict__ lq2, const float* __restrict__ lk2,
    const float* __restrict__ gamma) {
  __shared__ u16 K1s[64 * 64];
  __shared__ u16 K2s[64 * 64];
  __shared__ u16 VTs[128 * 64];
  __shared__ u16 Ps[2 * 2 * 32 * 64];   // [q-group][stream][32 q][64 kv]
  __shared__ float Lr[2][2][2][32];     // [q-group][stream][dh][q]
  __shared__ float Sr[2][2][32];        // [q-group][dh][q]

  const int g = blockIdx.x;       // 1024 blocks
  const int xcd = g & 7;
  const int gi = g >> 3;          // 0..127
  const int bh = xcd * 4 + (gi >> 5);
  const int qt = gi & 31;         // 32 q-tiles of 64 rows
  const int b = bh >> 4, h = bh & 15;

  const int tid = threadIdx.x, lane = tid & 63, wv = tid >> 6;
  const int qg = wv >> 1;         // q-group (0,1)
  const int dh = wv & 1;          // d-half (0,1); also this wave's KT in QK^T
  const int l31 = lane & 31;
  const int hi16 = (lane >> 5) * 16;
  const int hi8 = (lane >> 5) * 8;
  const int hi4 = (lane >> 5) * 4;

  float d1 = lq1[lane] * lk1[lane];
  float d2 = lq2[lane] * lk2[lane];
#pragma unroll
  for (int off = 32; off; off >>= 1) { d1 += __shfl_xor(d1, off); d2 += __shfl_xor(d2, off); }
  const float lam = __expf(d1) - __expf(d2) + LAMBDA_INIT_F;

  const int qbase = qt * 64 + qg * 32;
  const u16* qp1 = qkv + (size_t)(b * S_LEN + qbase + l31) * QKV_N + (2 * h) * 64;
  const u16* qp2 = qp1 + 64;
  short8 q1f0 = *(const short8*)(qp1 + hi8);
  short8 q1f1 = *(const short8*)(qp1 + 16 + hi8);
  short8 q1f2 = *(const short8*)(qp1 + 32 + hi8);
  short8 q1f3 = *(const short8*)(qp1 + 48 + hi8);
  short8 q2f0 = *(const short8*)(qp2 + hi8);
  short8 q2f1 = *(const short8*)(qp2 + 16 + hi8);
  short8 q2f2 = *(const short8*)(qp2 + 32 + hi8);
  short8 q2f3 = *(const short8*)(qp2 + 48 + hi8);

  f32x16 o1t0 = {}, o1t1 = {}, o2t0 = {}, o2t1 = {};
  float l1p = 0.f, l2p = 0.f;

  const int gl_row = wv * 8 + (lane >> 3);
  const int gl_cb  = ((lane & 7) ^ (lane >> 3)) * 8;
  u16* k1d = &K1s[(wv * 8) * 64 + lane * 8];
  u16* k2d = &K2s[(wv * 8) * 64 + lane * 8];

  const int vkv = (tid & 31) * 2;
  const int vd0 = (tid >> 5) * 8;

  const u16* kb1 = qkv + (size_t)b * S_LEN * QKV_N + EMB + (2 * h) * 64;
  const u16* kb2 = kb1 + 64;
  const u16* vbp = qkv + (size_t)b * S_LEN * QKV_N + 2 * EMB + h * 128;

  char* K1c = (char*)K1s;
  char* K2c = (char*)K2s;
  char* VTc = (char*)VTs;
  char* P1c = (char*)&Ps[(qg * 2 + 0) * 32 * 64];
  char* P2c = (char*)&Ps[(qg * 2 + 1) * 32 * 64];

  for (int kv0 = 0; kv0 < S_LEN; kv0 += 64) {
    __syncthreads();
    {
      const u16* g1 = kb1 + (size_t)(kv0 + gl_row) * QKV_N + gl_cb;
      const u16* g2 = kb2 + (size_t)(kv0 + gl_row) * QKV_N + gl_cb;
      gload_lds16(g1, k1d);
      gload_lds16(g1 + (size_t)32 * QKV_N, k1d + 32 * 64);
      gload_lds16(g2, k2d);
      gload_lds16(g2 + (size_t)32 * QKV_N, k2d + 32 * 64);
    }
    {
      const u16* vs = vbp + (size_t)(kv0 + vkv) * QKV_N + vd0;
      short8 a0 = *(const short8*)vs;
      short8 a1 = *(const short8*)(vs + QKV_N);
      short8 b0 = *(const short8*)(vs + 64);
      short8 b1 = *(const short8*)(vs + QKV_N + 64);
#pragma unroll
      for (int j = 0; j < 8; j++) {
        unsigned pk0 = (unsigned)(u16)a0[j] | (((unsigned)(u16)a1[j]) << 16);
        *(unsigned*)(VTc + SW(vd0 + j, vkv * 2)) = pk0;
        unsigned pk1 = (unsigned)(u16)b0[j] | (((unsigned)(u16)b1[j]) << 16);
        *(unsigned*)(VTc + SW(vd0 + 64 + j, vkv * 2)) = pk1;
      }
    }
    __syncthreads();

#define QKT(Kc, Q0, Q1, Q2, Q3, Pc, LSUM)                                        \
    do {                                                                         \
      f32x16 s = {};                                                             \
      int row = dh * 32 + l31;                                                   \
      s = MFMA32(*(const short8*)((Kc) + SW(row, 0  + hi16)), Q0, s);            \
      s = MFMA32(*(const short8*)((Kc) + SW(row, 32 + hi16)), Q1, s);            \
      s = MFMA32(*(const short8*)((Kc) + SW(row, 64 + hi16)), Q2, s);            \
      s = MFMA32(*(const short8*)((Kc) + SW(row, 96 + hi16)), Q3, s);            \
      _Pragma("unroll") for (int r = 0; r < 16; r += 4) {                        \
        float e0 = __builtin_amdgcn_exp2f(s[r]     * EXP2_SCALE);                \
        float e1 = __builtin_amdgcn_exp2f(s[r + 1] * EXP2_SCALE);                \
        float e2 = __builtin_amdgcn_exp2f(s[r + 2] * EXP2_SCALE);                \
        float e3 = __builtin_amdgcn_exp2f(s[r + 3] * EXP2_SCALE);                \
        LSUM += (e0 + e1) + (e2 + e3);                                           \
        unsigned lo_ = cvt_pk_bf16(e0, e1);                                      \
        unsigned hi_ = cvt_pk_bf16(e2, e3);                                      \
        *(unsigned long long*)((Pc) + SW(l31, dh * 64 + (r >> 2) * 16 + hi8)) =  \
            (unsigned long long)lo_ | ((unsigned long long)hi_ << 32);           \
      }                                                                          \
    } while (0)
    QKT(K1c, q1f0, q1f1, q1f2, q1f3, P1c, l1p);
    QKT(K2c, q2f0, q2f1, q2f2, q2f3, P2c, l2p);
#undef QKT
    __syncthreads();

    short8 p1f0 = *(const short8*)(P1c + SW(l31, 0  + hi16));
    short8 p1f1 = *(const short8*)(P1c + SW(l31, 32 + hi16));
    short8 p1f2 = *(const short8*)(P1c + SW(l31, 64 + hi16));
    short8 p1f3 = *(const short8*)(P1c + SW(l31, 96 + hi16));
    short8 p2f0 = *(const short8*)(P2c + SW(l31, 0  + hi16));
    short8 p2f1 = *(const short8*)(P2c + SW(l31, 32 + hi16));
    short8 p2f2 = *(const short8*)(P2c + SW(l31, 64 + hi16));
    short8 p2f3 = *(const short8*)(P2c + SW(l31, 96 + hi16));

#define PVD(DT, O1, O2)                                                          \
    do {                                                                         \
      int rw = (DT) * 32 + l31;                                                  \
      short8 va0 = *(const short8*)(VTc + SW(rw, 0  + hi16));                    \
      short8 va1 = *(const short8*)(VTc + SW(rw, 32 + hi16));                    \
      short8 va2 = *(const short8*)(VTc + SW(rw, 64 + hi16));                    \
      short8 va3 = *(const short8*)(VTc + SW(rw, 96 + hi16));                    \
      O1 = MFMA32(va0, p1f0, O1); O1 = MFMA32(va1, p1f1, O1);                    \
      O1 = MFMA32(va2, p1f2, O1); O1 = MFMA32(va3, p1f3, O1);                    \
      O2 = MFMA32(va0, p2f0, O2); O2 = MFMA32(va1, p2f1, O2);                    \
      O2 = MFMA32(va2, p2f2, O2); O2 = MFMA32(va3, p2f3, O2);                    \
    } while (0)
    PVD(dh * 2 + 0, o1t0, o2t0);
    PVD(dh * 2 + 1, o1t1, o2t1);
#undef PVD
  }

  // ---- epilogue ----
  float l1 = l1p + __shfl_xor(l1p, 32);
  float l2 = l2p + __shfl_xor(l2p, 32);
  if (lane < 32) { Lr[qg][0][dh][l31] = l1; Lr[qg][1][dh][l31] = l2; }
  __syncthreads();
  const float inv1 = 1.f / (Lr[qg][0][0][l31] + Lr[qg][0][1][l31]);
  const float inv2 = 1.f / (Lr[qg][1][0][l31] + Lr[qg][1][1][l31]);

  float ss = 0.f;
#define COMB(O1, O2)                                                   \
  _Pragma("unroll") for (int i = 0; i < 16; i++) {                     \
    float a = O1[i] * inv1 - lam * (O2[i] * inv2);                     \
    O1[i] = a;                                                         \
    ss += a * a;                                                       \
  }
  COMB(o1t0, o2t0) COMB(o1t1, o2t1)
#undef COMB
  ss += __shfl_xor(ss, 32);
  if (lane < 32) Sr[qg][dh][l31] = ss;
  __syncthreads();
  const float SS = Sr[qg][0][l31] + Sr[qg][1][l31];
  const float sc2 = rsqrtf(SS * (1.f / 128.f) + 1e-5f) * ONE_MINUS_LI;

  u16* orow = attnb + (size_t)(b * S_LEN + qbase + l31) * EMB + h * 128;
#define WRT(O1, DT)                                                             \
  _Pragma("unroll") for (int gg = 0; gg < 4; gg++) {                            \
    int d = dh * 64 + (DT) * 32 + gg * 8 + hi4;                                 \
    f32x4 gv = *(const f32x4*)&gamma[d];                                        \
    unsigned wlo = cvt_pk_bf16(O1[4 * gg] * gv[0] * sc2, O1[4 * gg + 1] * gv[1] * sc2); \
    unsigned whi = cvt_pk_bf16(O1[4 * gg + 2] * gv[2] * sc2, O1[4 * gg + 3] * gv[3] * sc2); \
    *(unsigned long long*)&orow[d] = (unsigned long long)wlo | ((unsigned long long)whi << 32); \
  }
  WRT(o1t0, 0) WRT(o1t1, 1)
#undef WRT
}

// ---------------- launcher ----------------
extern "C" void kernel_launch(void* const* d_in, const int* in_sizes, int n_in,
                              void* d_out, int out_size, void* d_ws, size_t ws_size,
                              hipStream_t stream) {
  (void)in_sizes; (void)n_in; (void)out_size; (void)ws_size;
  const float* x   = (const float*)d_in[0];
  const float* Wq  = (const float*)d_in[1];
  const float* Wk  = (const float*)d_in[2];
  const float* Wv  = (const float*)d_in[3];
  const float* Wo  = (const float*)d_in[4];
  const float* lq1 = (const float*)d_in[5];
  const float* lk1 = (const float*)d_in[6];
  const float* lq2 = (const float*)d_in[7];
  const float* lk2 = (const float*)d_in[8];
  const float* gam = (const float*)d_in[9];

  char* ws = (char*)d_ws;
  u16* xb    = (u16*)(ws);                          // 4096x2048 bf16
  u16* Wcat  = (u16*)(ws + 16777216);               // 6144x2048 bf16
  u16* Wob   = (u16*)(ws + 41943040);               // 2048x2048 bf16
  u16* qkv   = (u16*)(ws + 50331648);               // 4096x6144 bf16
  u16* attnb = xb;                                  // alias: x dead after QKV GEMM

  const int NE = EMB * EMB;
  cvt_all<<<(6 * (NE / 4)) / 256, 256, 0, stream>>>(x, Wq, Wk, Wv, Wo, xb, Wcat, Wob);

  dim3 g1(4096 / 128, QKV_N / 128);
  gemm_bt<1><<<g1, 256, 0, stream>>>(xb, Wcat, qkv, 4096, QKV_N, EMB);

  rope_kernel<<<(4096 * 64 * 32) / 256, 256, 0, stream>>>(qkv);

  attn_kernel<<<1024, 256, 0, stream>>>(qkv, attnb, lq1, lk1, lq2, lk2, gam);

  dim3 g2(4096 / 128, EMB / 128);
  gemm_bt<0><<<g2, 256, 0, stream>>>(attnb, Wob, d_out, 4096, EMB, EMB);
}